// Round 4
// baseline (1456.647 us; speedup 1.0000x reference)
//
#include <hip/hip_runtime.h>

// Problem constants (from reference)
#define F_DIM 14
#define H1D 16
#define H2D 32
#define H3D 16
#define E_DIM 64
// table size = F_DIM * E_DIM = 896 floats = 224 float4; row = 3584 B

// Math identity: LayerNorm over a singleton dim gives (x-x)/sqrt(eps)*gamma+beta
// = beta, independent of x. So out[b,n,f*64+e] = MLP_f(beta[f])[e] + b4[f,e] +
// emb[f,e] — a 896-float table broadcast over all 400k rows. Pure write-BW
// problem: 1.4336 GB of stores.
//
// R3 lesson (prev session): nontemporal stores and per-block fused table
// recompute both regressed. Plain cached dwordx4 stores are the right path.
//
// R4: the harness fill kernel proves pure stores reach ~6.25 TB/s on this
// buffer. Restructure the broadcast to look like the fill: each block owns
// ONE contiguous span and streams it sequentially. LCM(224,256)=1792 float4
// = 8 rows, so per 8-row group thread t always writes table columns
// (t+32k)%224, k=0..6 -> preload 7 float4 into registers; main loop is
// 7 independent dwordx4 stores + one add, no loads, no modulo.
//
// R5/R6/R7: identical resubmits — R4-R6 benches all failed with
// GPUAcquisitionTimeout (broker infra at capacity; no measurement taken).

__device__ __forceinline__ float gelu_exact(float x) {
    // jax.nn.gelu(approximate=False) = 0.5 * x * (1 + erf(x / sqrt(2)))
    return 0.5f * x * (1.0f + erff(x * 0.70710678118654752440f));
}

// Kernel 1: compute the 896-entry table. One block, 896 threads; thread t
// handles (f = t/64, e = t%64); each thread redundantly runs its feature's
// ~1k-MAC erf chain — trivial cost, weights are L1-resident.
__global__ void build_table_kernel(const float* __restrict__ beta,
                                   const float* __restrict__ W1,
                                   const float* __restrict__ b1,
                                   const float* __restrict__ W2,
                                   const float* __restrict__ b2,
                                   const float* __restrict__ W3,
                                   const float* __restrict__ b3,
                                   const float* __restrict__ W4,
                                   const float* __restrict__ b4,
                                   const float* __restrict__ emb,
                                   float* __restrict__ table) {
    const int tid = (int)threadIdx.x;          // 0..895
    const int f = tid >> 6;                    // feature index
    const int e = tid & 63;                    // embedding index
    if (f >= F_DIM) return;

    const float v = beta[f];                   // the LayerNorm(1) output

    float h1[H1D], h2[H2D], h3[H3D];
    #pragma unroll
    for (int k = 0; k < H1D; ++k)
        h1[k] = gelu_exact(v * W1[f * H1D + k] + b1[f * H1D + k]);

    #pragma unroll
    for (int j = 0; j < H2D; ++j) {
        float acc = b2[f * H2D + j];
        #pragma unroll
        for (int k = 0; k < H1D; ++k)
            acc += h1[k] * W2[(f * H1D + k) * H2D + j];
        h2[j] = gelu_exact(acc);
    }

    #pragma unroll
    for (int j = 0; j < H3D; ++j) {
        float acc = b3[f * H3D + j];
        #pragma unroll
        for (int k = 0; k < H2D; ++k)
            acc += h2[k] * W3[(f * H2D + k) * H3D + j];
        h3[j] = gelu_exact(acc);
    }

    float acc = b4[f * E_DIM + e] + emb[f * E_DIM + e];
    #pragma unroll
    for (int m = 0; m < H3D; ++m)
        acc += h3[m] * W4[(f * H3D + m) * E_DIM + e];

    table[tid] = acc;
}

// Kernel 2: stream the table over all rows, fill-kernel style.
// Each block owns a contiguous span of 8-row groups (1 group = 1792 float4 =
// 28 KB). Thread t's 7 table columns within a group are fixed: (t+32k)%224.
// Note on the table-aliases-out fallback: every value stored at offset o
// equals table[o%224], so even if block 0 overwrites the table region before
// a late block reads it, the values read are identical.
__global__ __launch_bounds__(256) void broadcast_stream_kernel(
        const float4* __restrict__ table4,
        float4* __restrict__ out4,
        int groups_total,          // total4 / 1792
        int groups_per_block,
        int total4) {
    const int t = (int)threadIdx.x;

    // Preload the 7 table entries this thread ever needs (L1/L2 hits).
    float4 tv0 = table4[(t       ) % 224];
    float4 tv1 = table4[(t +  32) % 224];
    float4 tv2 = table4[(t +  64) % 224];
    float4 tv3 = table4[(t +  96) % 224];
    float4 tv4 = table4[(t + 128) % 224];
    float4 tv5 = table4[(t + 160) % 224];
    float4 tv6 = table4[(t + 192) % 224];

    int g0 = (int)blockIdx.x * groups_per_block;
    int g1 = g0 + groups_per_block;
    if (g1 > groups_total) g1 = groups_total;

    int base = g0 * 1792 + t;                  // fits in int: total4 < 2^27
    for (int g = g0; g < g1; ++g, base += 1792) {
        out4[base           ] = tv0;
        out4[base +  256 * 1] = tv1;
        out4[base +  256 * 2] = tv2;
        out4[base +  256 * 3] = tv3;
        out4[base +  256 * 4] = tv4;
        out4[base +  256 * 5] = tv5;
        out4[base +  256 * 6] = tv6;
    }

    // Generic tail for shapes where total4 % 1792 != 0 (empty for this
    // problem: 89,600,000 = 50,000 * 1792).
    int tail = groups_total * 1792;
    for (int i = tail + (int)(blockIdx.x * blockDim.x) + t; i < total4;
         i += (int)(gridDim.x * blockDim.x))
        out4[i] = table4[i % 224];
}

extern "C" void kernel_launch(void* const* d_in, const int* in_sizes, int n_in,
                              void* d_out, int out_size, void* d_ws, size_t ws_size,
                              hipStream_t stream) {
    // setup_inputs order: x, gamma, beta, W1, b1, W2, b2, W3, b3, W4, b4, emb
    const float* beta = (const float*)d_in[2];
    const float* W1   = (const float*)d_in[3];
    const float* b1   = (const float*)d_in[4];
    const float* W2   = (const float*)d_in[5];
    const float* b2   = (const float*)d_in[6];
    const float* W3   = (const float*)d_in[7];
    const float* b3   = (const float*)d_in[8];
    const float* W4   = (const float*)d_in[9];
    const float* b4   = (const float*)d_in[10];
    const float* emb  = (const float*)d_in[11];

    float* out = (float*)d_out;

    // Table scratch: prefer d_ws; fall back to the head of d_out (row 0 of the
    // output IS the table, and the broadcast rewrites it with identical values).
    float* table = (ws_size >= (size_t)(F_DIM * E_DIM * sizeof(float)))
                       ? (float*)d_ws : out;

    build_table_kernel<<<1, F_DIM * E_DIM, 0, stream>>>(
        beta, W1, b1, W2, b2, W3, b3, W4, b4, emb, table);

    const int total4 = out_size / 4;                 // 89,600,000 float4
    const int groups_total = total4 / 1792;          // 50,000 8-row groups
    const int blocks = 2000;                         // all co-resident (<=2048)
    const int gpb = (groups_total + blocks - 1) / blocks;   // 25

    broadcast_stream_kernel<<<blocks, 256, 0, stream>>>(
        (const float4*)table, (float4*)out, groups_total, gpb, total4);
}